// Round 1
// baseline (302.869 us; speedup 1.0000x reference)
//
#include <hip/hip_runtime.h>

#define N_NODES 100000
#define N_EDGES 1250000
#define D 64
#define NPB 256                  // nodes per scan bucket
#define NB  391                  // ceil(N_NODES / NPB)
#define NPAD2 (NB * NPB)         // 100096
#define DUMMY N_NODES            // featn[DUMMY] is a zero row
#define HP 68                    // LDS leading-dim pad (16B-aligned float4 rows)
#define SSP_CAP 1950208          // >= N_EDGES + 7*N_NODES (worst-case pad-to-8)

// ---------------- K0: zero degree array ----------------
__global__ __launch_bounds__(256) void zero_kernel(int* __restrict__ deg) {
    int i = blockIdx.x * 256 + threadIdx.x;
    if (i < NPAD2) deg[i] = 0;
}

// ---------------- K1: degree count (int4-vectorized) ----------------
__global__ __launch_bounds__(256) void degree_kernel(const int* __restrict__ dst,
                                                     int* __restrict__ deg) {
    int i = blockIdx.x * 256 + threadIdx.x;
    if (i < N_EDGES / 4) {
        int4 d = ((const int4*)dst)[i];
        atomicAdd(&deg[d.x], 1);
        atomicAdd(&deg[d.y], 1);
        atomicAdd(&deg[d.z], 1);
        atomicAdd(&deg[d.w], 1);
    }
}

// ---------------- K2: per-bucket scan of padded degrees + norm ----------------
__global__ __launch_bounds__(256) void scan_bucket_kernel(const int* __restrict__ deg,
                                                          int* __restrict__ pbeg,
                                                          int* __restrict__ pdega,
                                                          float* __restrict__ norm,
                                                          int* __restrict__ bsum) {
    __shared__ int sc[256];
    int b = blockIdx.x, t = threadIdx.x;
    int n = b * NPB + t;
    int d = deg[n];
    int pd = (d + 7) & ~7;       // deg==0 -> pdeg==0
    int inc = pd;
    sc[t] = inc;
    __syncthreads();
    for (int off = 1; off < 256; off <<= 1) {
        int y = (t >= off) ? sc[t - off] : 0;
        __syncthreads();
        inc += y; sc[t] = inc;
        __syncthreads();
    }
    pbeg[n]  = inc - pd;         // local exclusive offset within bucket
    pdega[n] = pd;
    norm[n]  = rsqrtf((float)(d < 1 ? 1 : d));
    if (t == 255) bsum[b] = inc; // bucket total
}

// ---------------- K3: single-block scan of bucket totals ----------------
__global__ __launch_bounds__(512) void scan_bsum_kernel(const int* __restrict__ bsum,
                                                        int* __restrict__ bbase) {
    __shared__ int sc[512];
    int t = threadIdx.x;
    int v = (t < NB) ? bsum[t] : 0;
    int inc = v;
    sc[t] = inc;
    __syncthreads();
    for (int off = 1; off < 512; off <<= 1) {
        int y = (t >= off) ? sc[t - off] : 0;
        __syncthreads();
        inc += y; sc[t] = inc;
        __syncthreads();
    }
    if (t < NB) bbase[t] = inc - v;  // exclusive base per bucket
}

// ---------------- K4: finalize offsets + cursors + pad fill + fused featn prep ----------------
__global__ __launch_bounds__(1024) void finalize_kernel(const int* __restrict__ deg,
                                                        int* __restrict__ pbeg,
                                                        const int* __restrict__ pdega,
                                                        int* __restrict__ cur,
                                                        const int* __restrict__ bbase,
                                                        int* __restrict__ ssp,
                                                        const float* __restrict__ norm,
                                                        const float* __restrict__ feat,
                                                        unsigned short* __restrict__ featn) {
    int b = blockIdx.x, t = threadIdx.x;
    int n0 = b * NPB;
    if (t < NPB) {
        int n = n0 + t;
        int pb = pbeg[n] + bbase[b];
        pbeg[n] = pb;
        cur[n]  = pb;
        int d = deg[n], pd = pdega[n];
        for (int k = pb + d; k < pb + pd; ++k) ssp[k] = DUMMY;  // <=7 iters
    }

    // fused prep for this bucket's 256 nodes (rows >= N_NODES zeroed)
    for (int idx = t; idx < NPB * 16; idx += 1024) {
        int nl = idx >> 4;
        int n = n0 + nl;
        uint2 r = make_uint2(0u, 0u);
        if (n < N_NODES) {
            float nn = norm[n];
            float4 f = ((const float4*)feat)[(size_t)n * 16 + (idx & 15)];
            auto cvt = [](float x) -> unsigned {
                unsigned u = __float_as_uint(x);
                return (u + 0x7fff + ((u >> 16) & 1)) >> 16;
            };
            r.x = cvt(f.x * nn) | (cvt(f.y * nn) << 16);
            r.y = cvt(f.z * nn) | (cvt(f.w * nn) << 16);
        }
        ((uint2*)featn)[(size_t)n * 16 + (idx & 15)] = r;
    }
}

// ---------------- K5: atomic scatter into padded CSR ----------------
__global__ __launch_bounds__(512) void scatter_kernel(const int* __restrict__ src,
                                                      const int* __restrict__ dst,
                                                      int* __restrict__ cur,
                                                      int* __restrict__ ssp) {
    int i = blockIdx.x * 512 + threadIdx.x;
    if (i < N_EDGES / 2) {
        int2 d = ((const int2*)dst)[i];
        int2 s = ((const int2*)src)[i];
        int p0 = atomicAdd(&cur[d.x], 1); ssp[p0] = s.x;
        int p1 = atomicAdd(&cur[d.y], 1); ssp[p1] = s.y;
    }
}

// ---------------- fused gather + GEMM: 64 nodes per 1024-thread block ----------------
#define ACC_EDGE(ACC, J) do {                                         \
        int s_ = ssp[(J)];                                            \
        uint2 r_ = *(const uint2*)&featn[(size_t)s_ * D + m * 4];     \
        ACC.x += __uint_as_float(r_.x << 16);                         \
        ACC.y += __uint_as_float(r_.x & 0xffff0000u);                 \
        ACC.z += __uint_as_float(r_.y << 16);                         \
        ACC.w += __uint_as_float(r_.y & 0xffff0000u);                 \
    } while (0)
#define ACC4(ACC, J) { ACC_EDGE(ACC, (J) + q); ACC_EDGE(ACC, (J) + 4 + q); \
                       ACC_EDGE(ACC, (J) + 8 + q); ACC_EDGE(ACC, (J) + 12 + q); }
#define ACC2(ACC, J) { ACC_EDGE(ACC, (J) + q); ACC_EDGE(ACC, (J) + 4 + q); }

__global__ __launch_bounds__(1024) void gather_gemm_kernel(const unsigned short* __restrict__ featn,
                                                           const int* __restrict__ ssp,
                                                           const int* __restrict__ pbeg,
                                                           const int* __restrict__ pdega,
                                                           const float* __restrict__ norm,
                                                           const float* __restrict__ weight,
                                                           const float* __restrict__ bias,
                                                           float* __restrict__ out) {
    __shared__ float Hcol[D * HP];   // Hcol[k][n_local]
    __shared__ float Wt[D * HP];     // Wt[k][d]
    int tid = threadIdx.x;
    int base = blockIdx.x * 64;

    // stage W^T (k-major) with all 1024 threads
    #pragma unroll
    for (int i = tid; i < D * D; i += 1024) {
        int c = i & 63, dd = i >> 6;
        Wt[c * HP + dd] = weight[dd * D + c];
    }

    // phase 1: gather. wave w handles 4 nodes, processed as 2 interleaved pairs.
    int w = tid >> 6;
    int lane = tid & 63;
    int q = lane >> 4, m = lane & 15;

    #pragma unroll
    for (int pr = 0; pr < 2; ++pr) {
        int nA = base + w * 4 + pr * 2;
        int nB = nA + 1;
        int begA = pbeg[nA], endA = begA + pdega[nA];
        int begB = pbeg[nB], endB = begB + pdega[nB];
        float4 aA = make_float4(0.f, 0.f, 0.f, 0.f);
        float4 aB = make_float4(0.f, 0.f, 0.f, 0.f);
        int jA = begA, jB = begB;
        while (jA + 16 <= endA && jB + 16 <= endB) {   // 8 row-loads in flight
            ACC4(aA, jA); ACC4(aB, jB);
            jA += 16; jB += 16;
        }
        for (; jA + 16 <= endA; jA += 16) ACC4(aA, jA);
        for (; jB + 16 <= endB; jB += 16) ACC4(aB, jB);
        if (jA < endA) ACC2(aA, jA);                    // exactly 8 remain
        if (jB < endB) ACC2(aB, jB);

        #pragma unroll
        for (int mask = 16; mask <= 32; mask <<= 1) {
            aA.x += __shfl_xor(aA.x, mask); aA.y += __shfl_xor(aA.y, mask);
            aA.z += __shfl_xor(aA.z, mask); aA.w += __shfl_xor(aA.w, mask);
            aB.x += __shfl_xor(aB.x, mask); aB.y += __shfl_xor(aB.y, mask);
            aB.z += __shfl_xor(aB.z, mask); aB.w += __shfl_xor(aB.w, mask);
        }
        float nnA = norm[nA], nnB = norm[nB];
        // lane (q,m) writes component q of column group m -> Hcol[4m+q][nl]
        float hA = (q == 0) ? aA.x : (q == 1) ? aA.y : (q == 2) ? aA.z : aA.w;
        float hB = (q == 0) ? aB.x : (q == 1) ? aB.y : (q == 2) ? aB.z : aB.w;
        int k = 4 * m + q;
        Hcol[k * HP + (w * 4 + pr * 2)]     = hA * nnA;
        Hcol[k * HP + (w * 4 + pr * 2 + 1)] = hB * nnB;
    }
    __syncthreads();

    // phase 2: 64x64 GEMM from LDS, first 256 threads, 4x4 register tiles
    if (tid < 256) {
        int tx = tid & 15, ty = tid >> 4;
        float acc[4][4] = {};
        #pragma unroll 8
        for (int k = 0; k < D; ++k) {
            float4 a = *(const float4*)&Hcol[k * HP + ty * 4];
            float4 b = *(const float4*)&Wt[k * HP + tx * 4];
            acc[0][0] += a.x * b.x; acc[0][1] += a.x * b.y; acc[0][2] += a.x * b.z; acc[0][3] += a.x * b.w;
            acc[1][0] += a.y * b.x; acc[1][1] += a.y * b.y; acc[1][2] += a.y * b.z; acc[1][3] += a.y * b.w;
            acc[2][0] += a.z * b.x; acc[2][1] += a.z * b.y; acc[2][2] += a.z * b.z; acc[2][3] += a.z * b.w;
            acc[3][0] += a.w * b.x; acc[3][1] += a.w * b.y; acc[3][2] += a.w * b.z; acc[3][3] += a.w * b.w;
        }
        float4 bv = *(const float4*)&bias[tx * 4];
        #pragma unroll
        for (int i = 0; i < 4; ++i) {
            int n = base + ty * 4 + i;
            if (n < N_NODES) {
                *(float4*)&out[(size_t)n * D + tx * 4] =
                    make_float4(acc[i][0] + bv.x, acc[i][1] + bv.y,
                                acc[i][2] + bv.z, acc[i][3] + bv.w);
            }
        }
    }
}

extern "C" void kernel_launch(void* const* d_in, const int* in_sizes, int n_in,
                              void* d_out, int out_size, void* d_ws, size_t ws_size,
                              hipStream_t stream) {
    const float* feat   = (const float*)d_in[0];
    const int*   src    = (const int*)d_in[1];
    const int*   dst    = (const int*)d_in[2];
    const float* weight = (const float*)d_in[3];
    const float* bias   = (const float*)d_in[4];
    float* out = (float*)d_out;

    // workspace layout (4-byte units); high water ~22.2 MB
    int* w = (int*)d_ws;
    int*   deg   = w;                         // [NPAD2]
    int*   cur   = deg + NPAD2;               // [NPAD2]
    int*   pbeg  = cur + NPAD2;               // [NPAD2]
    int*   pdega = pbeg + NPAD2;              // [NPAD2]
    float* norm  = (float*)(pdega + NPAD2);   // [NPAD2]
    int*   bsum  = (int*)(norm + NPAD2);      // [NB]
    int*   bbase = bsum + NB;                 // [NB]
    int*   ssp   = bbase + NB;                // [SSP_CAP]
    size_t featn_off = 5 * (size_t)NPAD2 + 2 * (size_t)NB + (size_t)SSP_CAP;
    featn_off = (featn_off + 3) & ~(size_t)3; // 16B-align
    unsigned short* featn = (unsigned short*)(w + featn_off); // [NPAD2*D] bf16

    zero_kernel       <<<(NPAD2 + 255) / 256, 256, 0, stream>>>(deg);
    degree_kernel     <<<(N_EDGES / 4 + 255) / 256, 256, 0, stream>>>(dst, deg);
    scan_bucket_kernel<<<NB, 256, 0, stream>>>(deg, pbeg, pdega, norm, bsum);
    scan_bsum_kernel  <<<1, 512, 0, stream>>>(bsum, bbase);
    finalize_kernel   <<<NB, 1024, 0, stream>>>(deg, pbeg, pdega, cur, bbase, ssp, norm, feat, featn);
    scatter_kernel    <<<(N_EDGES / 2 + 511) / 512, 512, 0, stream>>>(src, dst, cur, ssp);
    gather_gemm_kernel<<<(N_NODES + 63) / 64, 1024, 0, stream>>>(featn, ssp, pbeg, pdega, norm,
                                                                 weight, bias, out);
}